// Round 4
// baseline (341.461 us; speedup 1.0000x reference)
//
#include <hip/hip_runtime.h>
#include <stdint.h>

typedef short bf16x8 __attribute__((ext_vector_type(8)));
typedef float f32x4 __attribute__((ext_vector_type(4)));

__device__ __forceinline__ void async_cp16(const void* g, short* lds) {
  __builtin_amdgcn_global_load_lds(
      (const __attribute__((address_space(1))) void*)g,
      (__attribute__((address_space(3))) void*)lds, 16, 0, 0);
}

// tanh-approx GELU via sigmoid; |err| < ~1e-3 abs, threshold is 4.3e-2.
__device__ __forceinline__ float gelu_f(float v) {
  float z = 1.5957691216057308f * (v + 0.044715f * v * v * v);
  return __fdividef(v, 1.0f + __expf(-z));
}

__device__ __forceinline__ short f2bf(float x) {  // RNE f32->bf16
  uint32_t u = __float_as_uint(x);
  u += 0x7fffu + ((u >> 16) & 1u);
  return (short)(u >> 16);
}

// ---------------------------------------------------------------------------
// One-launch prep: fp32 -> bf16 cast of X + per-expert transposes of W1/W2.
// ---------------------------------------------------------------------------
__global__ __launch_bounds__(256)
void prep_all(const float* __restrict__ x, const float* __restrict__ w1,
              const float* __restrict__ w2, short* __restrict__ Xb,
              short* __restrict__ w1t, short* __restrict__ w2t)
{
  __shared__ __align__(16) short T[64][72];
  const int b = blockIdx.x;
  const int t = threadIdx.x;

  if (b < 2048) {                       // ---- X cast ----
    const int idx = (b * 256 + t) * 8;
    bf16x8 o;
#pragma unroll
    for (int u = 0; u < 8; ++u) o[u] = f2bf(x[idx + u]);
    *(bf16x8*)(Xb + idx) = o;
    return;
  }

  const float* src; short* dst; int e, r0, c0, R, C;
  if (b < 3072) {                       // ---- W1 ----
    int idx = b - 2048; e = idx >> 6; int rem = idx & 63;
    r0 = (rem >> 3) * 64; c0 = (rem & 7) * 64; R = 512; C = 512;
    src = w1; dst = w1t;
  } else {                              // ---- W2 ----
    int idx = b - 3072; e = idx >> 4; int rem = idx & 15;
    r0 = (rem >> 1) * 64; c0 = (rem & 1) * 64; R = 512; C = 128;
    src = w2; dst = w2t;
  }
  const float* s = src + (size_t)e * R * C;
  short* d       = dst + (size_t)e * R * C;
  const int i = t >> 3, j8 = t & 7;
#pragma unroll
  for (int p = 0; p < 2; ++p) {
    int ii = i + p * 32;
#pragma unroll
    for (int u = 0; u < 8; ++u)
      T[ii][j8 * 8 + u] = f2bf(s[(size_t)(r0 + ii) * C + c0 + j8 * 8 + u]);
  }
  __syncthreads();
#pragma unroll
  for (int p = 0; p < 2; ++p) {
    int ii = i + p * 32;
    bf16x8 v;
#pragma unroll
    for (int u = 0; u < 8; ++u) v[u] = T[j8 * 8 + u][ii];
    *(bf16x8*)(d + (size_t)(c0 + ii) * R + r0 + j8 * 8) = v;
  }
}

// ---------------------------------------------------------------------------
// Fused experts. Block = 128-token tile x 1 expert, 4 waves (2x2 of 64x64).
// R11: back to the R7 all-__syncthreads discipline (R8-R10's counted-vmcnt
// was a regime-gate miss: loads are L2-hot, drain was never the stall; the
// junk tail cost +45MB FETCH). The real stall is fixed cost PER SLICE
// (ds_read latency + barrier skew, ~1.6k cy) paid 22x/hc. Fix: BK=64
// slices -> 2x matrix work per barrier, 11 barriers/hc instead of 22.
//  - Xs/Ws [128][64] shorts (128B rows): XOR slot-swizzle slot=q^(row&7),
//    applied on the per-lane GLOBAL source (rule 21), LDS dest linear.
//  - HL [128][128] shorts, byte-XOR ^((tok&7)<<4), aliases exactly Xs0+Xs1.
//  - Phase 2: 2 slices of K=64, staged W2 s0 at kk=7, s1 after GUARD-A;
//    s0+s1 compute back-to-back (no barrier: disjoint bufs, read-only HL).
//  - LDS 64 KB -> 2 blocks/CU (VGPR-capped at 2 waves/SIMD anyway).
//  - No DMA outstanding at endpgm (last stage drained at B1).
// ---------------------------------------------------------------------------
__global__ __launch_bounds__(256, 2)
void moe_kernel(const short* __restrict__ Xb, const short* __restrict__ W1T,
                const short* __restrict__ W2T, void* __restrict__ O, int staged)
{
  __shared__ __align__(16) short SM[32768];        // 64 KB
  short* const Ws0 = SM;                           // [128][64]
  short* const Ws1 = SM + 8192;
  short* const Xs0 = SM + 16384;                   // [128][64]
  short* const Xs1 = SM + 24576;
  char*  const HLb = (char*)(SM + 16384);          // [128][128] over Xs0+Xs1

  const int tid = threadIdx.x;
  const int l = tid & 63, w = tid >> 6;
  const int wm = w & 1, wn = w >> 1;
  const int e    = blockIdx.x >> 6;     // e-outer (L2 locality per XCD)
  const int tile = blockIdx.x & 63;

  // ---- staging lane constants: cp c covers rows (c*4+w)*8..+8, lane l ->
  // row +(l>>3), 16B slot (l&7). LDS fill is linear (base + l*16B); the
  // XOR swizzle slot=q^(row&7) is applied on the GLOBAL source address.
  const int lr8 = l >> 3, gs = (l & 7) ^ lr8;      // row&7 == lr8
  int ldso[4];
  const char *xg[4], *w1g[4], *w2g[4];
#pragma unroll
  for (int c = 0; c < 4; ++c) {
    int p = c * 4 + w;                             // 0..15
    int row = p * 8 + lr8;                         // 0..127
    ldso[c] = p * 512;                             // shorts (1KB per cp)
    xg[c]  = (const char*)Xb  + (size_t)(tile * 128 + row) * 1024 + gs * 16;
    w1g[c] = (const char*)W1T + (size_t)e * 524288 + (size_t)row * 1024 + gs * 16;
    w2g[c] = (const char*)W2T + (size_t)e * 131072 + (size_t)row * 1024 + gs * 16;
  }

  // ---- consumer lane constants. Global quad q=ks*4+g at row r lives in
  // LDS slot q^(r&7); r&7==lm&7 for all frag rows (t*16 steps).
  const int lm = l & 15, g = l >> 4;
  int sA[2], sB[2];
#pragma unroll
  for (int ks = 0; ks < 2; ++ks) {
    int sl = (ks * 4 + g) ^ (lm & 7);
    sA[ks] = (wm * 64 + lm) * 64 + sl * 8;
    sB[ks] = (wn * 64 + lm) * 64 + sl * 8;
  }
  const int hswz = (lm & 7) << 4;                  // HL read XOR (tok&7==lm&7)

  f32x4 acc2[4][4];
#pragma unroll
  for (int i = 0; i < 4; ++i)
#pragma unroll
    for (int j = 0; j < 4; ++j) acc2[i][j] = (f32x4){0.f, 0.f, 0.f, 0.f};

  // prologue: stage kk=0 into buf0
#pragma unroll
  for (int c = 0; c < 4; ++c) async_cp16(xg[c],  Xs0 + ldso[c]);
#pragma unroll
  for (int c = 0; c < 4; ++c) async_cp16(w1g[c], Ws0 + ldso[c]);

  for (int hc = 0; hc < 4; ++hc) {
    f32x4 acc1[4][4];
#pragma unroll
    for (int i = 0; i < 4; ++i)
#pragma unroll
      for (int j = 0; j < 4; ++j) acc1[i][j] = (f32x4){0.f, 0.f, 0.f, 0.f};

    const size_t w1o = (size_t)hc * 131072;        // 128 h-rows * 1024B

    // ---- phase 1: hidden[:, hc*128:+128] = X * W1, K=512 in 8 slices ----
#pragma unroll
    for (int kk = 0; kk < 8; ++kk) {
      __syncthreads();                             // bufs ready (vmcnt drained)
      if (kk < 7) {
        short* xb = ((kk + 1) & 1) ? Xs1 : Xs0;
        short* wb = ((kk + 1) & 1) ? Ws1 : Ws0;
#pragma unroll
        for (int c = 0; c < 4; ++c)
          async_cp16(xg[c] + (kk + 1) * 128,        xb + ldso[c]);
#pragma unroll
        for (int c = 0; c < 4; ++c)
          async_cp16(w1g[c] + w1o + (kk + 1) * 128, wb + ldso[c]);
      } else {                                     // W2 s=0 -> Ws0 (free: kk=6 done)
#pragma unroll
        for (int c = 0; c < 4; ++c)
          async_cp16(w2g[c] + hc * 256, Ws0 + ldso[c]);
      }
      const short* xb = (kk & 1) ? Xs1 : Xs0;
      const short* wb = (kk & 1) ? Ws1 : Ws0;
#pragma unroll
      for (int ks = 0; ks < 2; ++ks) {
        bf16x8 af[4], bfr[4];
#pragma unroll
        for (int t = 0; t < 4; ++t) af[t]  = *(const bf16x8*)(xb + sA[ks] + t * 1024);
#pragma unroll
        for (int t = 0; t < 4; ++t) bfr[t] = *(const bf16x8*)(wb + sB[ks] + t * 1024);
#pragma unroll
        for (int i = 0; i < 4; ++i)
#pragma unroll
          for (int j = 0; j < 4; ++j)
            acc1[i][j] = __builtin_amdgcn_mfma_f32_16x16x32_bf16(af[i], bfr[j], acc1[i][j], 0, 0, 0);
      }
    }

    __syncthreads();   // GUARD-A: all Xs/Ws phase-1 reads done; W2 s0 landed

    // stage W2 s=1 -> Ws1 (free since GUARD-A); lands by B1
#pragma unroll
    for (int c = 0; c < 4; ++c)
      async_cp16(w2g[c] + hc * 256 + 128, Ws1 + ldso[c]);

    // ---- GELU -> HL (aliases Xs0+Xs1; safe after GUARD-A) ----
#pragma unroll
    for (int i = 0; i < 4; ++i)
#pragma unroll
      for (int j = 0; j < 4; ++j)
#pragma unroll
        for (int r = 0; r < 4; ++r) {
          int tok = wm * 64 + i * 16 + g * 4 + r;
          int h   = wn * 64 + j * 16 + lm;
          int byo = (tok * 256 + h * 2) ^ ((tok & 7) << 4);
          *(short*)(HLb + byo) = f2bf(gelu_f(acc1[i][j][r]));
        }

    __syncthreads();   // B1: HL published; W2 s1 landed (vmcnt drained)

    // ---- phase 2: acc2 += gelu(chunk) * W2, K=128 in 2 slices, no barrier
    // between (disjoint Ws bufs, HL read-only) ----
#pragma unroll
    for (int s = 0; s < 2; ++s) {
      const short* wb = s ? Ws1 : Ws0;
#pragma unroll
      for (int ks = 0; ks < 2; ++ks) {
        bf16x8 af[4], bfr[4];
#pragma unroll
        for (int t = 0; t < 4; ++t) {
          int tok = wm * 64 + t * 16 + lm;
          int byo = (tok * 256 + s * 128 + ks * 64 + g * 16) ^ hswz;
          af[t] = *(const bf16x8*)(HLb + byo);
        }
#pragma unroll
        for (int t = 0; t < 4; ++t) bfr[t] = *(const bf16x8*)(wb + sB[ks] + t * 1024);
#pragma unroll
        for (int i = 0; i < 4; ++i)
#pragma unroll
          for (int j = 0; j < 4; ++j)
            acc2[i][j] = __builtin_amdgcn_mfma_f32_16x16x32_bf16(af[i], bfr[j], acc2[i][j], 0, 0, 0);
      }
    }

    __syncthreads();   // GUARD-B: HL reads + Ws reads done
    if (hc < 3) {      // stage next-hc kk=0 (drained at next kk=0 barrier)
#pragma unroll
      for (int c = 0; c < 4; ++c) async_cp16(xg[c], Xs0 + ldso[c]);
#pragma unroll
      for (int c = 0; c < 4; ++c) async_cp16(w1g[c] + w1o + 131072, Ws0 + ldso[c]);
    }
  }

  // ---- epilogue (no DMA outstanding: last stage drained at B1 of hc=3) ----
  const int d4 = wn * 64 + lm;
  const int lqr = g * 4;
  if (staged) {  // coalesced bf16: OUTs[e][row][d4]
    unsigned short* Ob = (unsigned short*)O;
    const size_t base = ((size_t)e * 8192 + tile * 128 + wm * 64 + lqr) * 128 + d4;
#pragma unroll
    for (int i = 0; i < 4; ++i)
#pragma unroll
      for (int r = 0; r < 4; ++r)
#pragma unroll
        for (int j = 0; j < 4; ++j)
          Ob[base + (size_t)(i * 16 + r) * 128 + j * 16] = (unsigned short)f2bf(acc2[i][j][r]);
  } else {       // direct strided fp32 fallback
    float* Of = (float*)O;
    const size_t rowb = (size_t)tile * 128 + wm * 64 + lqr;
    const size_t base = (rowb * 128 + d4) * 16 + e;
#pragma unroll
    for (int i = 0; i < 4; ++i)
#pragma unroll
      for (int r = 0; r < 4; ++r)
#pragma unroll
        for (int j = 0; j < 4; ++j)
          Of[base + (size_t)(i * 16 + r) * 2048 + j * 256] = acc2[i][j][r];
  }
}

// ---------------------------------------------------------------------------
// Permute: OUT[row][d4*16+e] (fp32) = OUTs[e][row][d4] (bf16). Block = 8 rows.
// ---------------------------------------------------------------------------
__global__ __launch_bounds__(256, 2)
void permute_kernel(const unsigned short* __restrict__ OUTs, float* __restrict__ OUT)
{
  __shared__ float T[8 * 16 * 132];     // 67.6 KB
  const int t = threadIdx.x;
  const int r0 = blockIdx.x * 8;
#pragma unroll
  for (int it = 0; it < 8; ++it) {
    int v = it * 256 + t;                       // bf16x8-id, [0,2048)
    int e = v >> 7, rem = v & 127, r = rem >> 4, q8 = rem & 15;
    bf16x8 d = *(const bf16x8*)(OUTs + ((size_t)e * 8192 + r0 + r) * 128 + q8 * 8);
#pragma unroll
    for (int u = 0; u < 8; ++u)
      T[(r * 16 + e) * 132 + q8 * 8 + u] =
          __uint_as_float(((uint32_t)(unsigned short)d[u]) << 16);
  }
  __syncthreads();
#pragma unroll
  for (int it = 0; it < 16; ++it) {
    int u = it * 256 + t;                       // vec4 id, [0,4096)
    int r = u >> 9;                             // [0,8)
    int c4 = (u & 511) * 4;                     // [0,2048)
    int d4 = c4 >> 4, e0 = c4 & 15;
    f32x4 o;
#pragma unroll
    for (int i = 0; i < 4; ++i) o[i] = T[(r * 16 + e0 + i) * 132 + d4];
    *(f32x4*)(OUT + (size_t)(r0 + r) * 2048 + c4) = o;
  }
}

extern "C" void kernel_launch(void* const* d_in, const int* in_sizes, int n_in,
                              void* d_out, int out_size, void* d_ws, size_t ws_size,
                              hipStream_t stream)
{
  const float* x  = (const float*)d_in[0];   // fp32 [8192][512]
  const float* w1 = (const float*)d_in[1];   // fp32 [16][512][512]
  const float* w2 = (const float*)d_in[2];   // fp32 [16][512][128]
  float* out = (float*)d_out;                // fp32 [8192][128][16]

  short* Xb  = (short*)d_ws;                 // 8.39 MB
  short* w1t = Xb + 4194304;                 // 8.39 MB
  short* w2t = w1t + 4194304;                // 2.10 MB
  unsigned short* OUTs = (unsigned short*)((char*)d_ws + 18874368);  // bf16, 33.5 MB
  const bool staged = ws_size >= 52428800ULL;

  prep_all<<<dim3(3328), 256, 0, stream>>>(x, w1, w2, Xb, w1t, w2t);
  moe_kernel<<<dim3(1024), 256, 0, stream>>>(Xb, w1t, w2t,
                                             staged ? (void*)OUTs : (void*)out,
                                             staged ? 1 : 0);
  if (staged)
    permute_kernel<<<dim3(1024), 256, 0, stream>>>(OUTs, out);
}

// Round 5
// 236.334 us; speedup vs baseline: 1.4448x; 1.4448x over previous
//
#include <hip/hip_runtime.h>
#include <stdint.h>

typedef short bf16x8 __attribute__((ext_vector_type(8)));
typedef float f32x4 __attribute__((ext_vector_type(4)));
typedef unsigned int uint4v __attribute__((ext_vector_type(4)));

__device__ __forceinline__ void async_cp16(const void* g, short* lds) {
  __builtin_amdgcn_global_load_lds(
      (const __attribute__((address_space(1))) void*)g,
      (__attribute__((address_space(3))) void*)lds, 16, 0, 0);
}

// tanh-approx GELU via sigmoid; |err| < ~1e-3 abs, threshold is 4.3e-2.
// Folded: -z = v * (-1.5957691 - 0.07135512*v^2)  (Horner, 3 VALU + expf).
__device__ __forceinline__ float gelu_f(float v) {
  float v2 = v * v;
  float t  = v * __builtin_fmaf(v2, -0.07135512f, -1.5957691f);
  return __fdividef(v, 1.0f + __expf(t));
}

// RNE f32 pair -> packed bf16x2 in one VALU op (v_cvt_pk_bf16_f32, gfx950;
// dst.lo = cvt(src0), dst.hi = cvt(src1)). Pure value dep, no hazards.
__device__ __forceinline__ uint32_t pk2(float a, float b) {
  uint32_t u;
  asm("v_cvt_pk_bf16_f32 %0, %1, %2" : "=v"(u) : "v"(a), "v"(b));
  return u;
}

// ---------------------------------------------------------------------------
// One-launch prep: fp32 -> bf16 cast of X + per-expert transposes of W1/W2.
// R12: conversions via cvt_pk pairs (4x fewer VALU than bit-twiddle f2bf).
// ---------------------------------------------------------------------------
__global__ __launch_bounds__(256)
void prep_all(const float* __restrict__ x, const float* __restrict__ w1,
              const float* __restrict__ w2, short* __restrict__ Xb,
              short* __restrict__ w1t, short* __restrict__ w2t)
{
  __shared__ __align__(16) short T[64][72];
  const int b = blockIdx.x;
  const int t = threadIdx.x;

  if (b < 2048) {                       // ---- X cast ----
    const int idx = (b * 256 + t) * 8;
    uint4v o;
#pragma unroll
    for (int u = 0; u < 4; ++u) o[u] = pk2(x[idx + 2 * u], x[idx + 2 * u + 1]);
    *(uint4v*)(Xb + idx) = o;
    return;
  }

  const float* src; short* dst; int e, r0, c0, R, C;
  if (b < 3072) {                       // ---- W1 ----
    int idx = b - 2048; e = idx >> 6; int rem = idx & 63;
    r0 = (rem >> 3) * 64; c0 = (rem & 7) * 64; R = 512; C = 512;
    src = w1; dst = w1t;
  } else {                              // ---- W2 ----
    int idx = b - 3072; e = idx >> 4; int rem = idx & 15;
    r0 = (rem >> 1) * 64; c0 = (rem & 1) * 64; R = 512; C = 128;
    src = w2; dst = w2t;
  }
  const float* s = src + (size_t)e * R * C;
  short* d       = dst + (size_t)e * R * C;
  const int i = t >> 3, j8 = t & 7;
#pragma unroll
  for (int p = 0; p < 2; ++p) {
    int ii = i + p * 32;
    const float* sr = s + (size_t)(r0 + ii) * C + c0 + j8 * 8;
    uint32_t* tw = (uint32_t*)&T[ii][j8 * 8];          // 4B-aligned
#pragma unroll
    for (int u = 0; u < 4; ++u) tw[u] = pk2(sr[2 * u], sr[2 * u + 1]);
  }
  __syncthreads();
#pragma unroll
  for (int p = 0; p < 2; ++p) {
    int ii = i + p * 32;
    bf16x8 v;
#pragma unroll
    for (int u = 0; u < 8; ++u) v[u] = T[j8 * 8 + u][ii];
    *(bf16x8*)(d + (size_t)(c0 + ii) * R + r0 + j8 * 8) = v;
  }
}

// ---------------------------------------------------------------------------
// Fused experts. Block = 128-token tile x 1 expert, 4 waves (2x2 of 64x64).
// R12 = R7's HW-proven structure EXACTLY (staging pattern, BK=32 dbuf,
// aliased 51.2 KB LDS, __syncthreads discipline — all untouched; R8-R11
// showed every mutation of these regresses: coarse counted-vmcnt −16%,
// BK=64+re-swizzle −88% via L2/FETCH explosion 56->268 MB). Changes are
// per-lane VALU only: GELU Horner fold + cvt_pk bf16 pair-conversion in
// the GELU spill and the epilogue (the two conversion-dense regions).
// launch_bounds(256,2): natural VGPR ~128; (256,3) triggers 84-VGPR tier
// + spills (R7 lesson). Block decode e-outer: consecutive blocks = same
// expert -> per-XCD L2 working set ~3 MB.
// staged==1: O = ws bf16 [16 e][8192 row][128 d4] (coalesced).
// staged==0: O = out fp32 [row][d4][16 e] (strided fallback).
// ---------------------------------------------------------------------------
__global__ __launch_bounds__(256, 2)
void moe_kernel(const short* __restrict__ Xb, const short* __restrict__ W1T,
                const short* __restrict__ W2T, void* __restrict__ O, int staged)
{
  __shared__ __align__(16) short SM[25600];        // 51.2 KB
  short* const Ws0 = SM;                           // [128][32]
  short* const Ws1 = SM + 4096;
  short* const Xs0 = SM + 8192;                    // aliased by HL
  short* const Xs1 = SM + 12288;                   // aliased by HL
  short* const HL  = SM + 8192;                    // [128][136], phase-2 only

  const int tid = threadIdx.x;
  const int l = tid & 63, w = tid >> 6;
  const int wm = w & 1, wn = w >> 1;
  const int e    = blockIdx.x >> 6;     // e-outer (L2 locality per XCD)
  const int tile = blockIdx.x & 63;

  // staging lane constants (lane -> base + lane*16B, packed [row][32 shorts])
  const int lrow = l >> 2, lq = l & 3;
  int ldso[2];
  const char *xg[2], *w1g[2], *w2g[2];
#pragma unroll
  for (int c = 0; c < 2; ++c) {
    int prow = w * 32 + c * 16 + lrow;                      // 0..127
    int qg = lq ^ ((prow >> 1) & 3);                        // XOR quad swizzle
    ldso[c] = (w * 32 + c * 16) * 32;
    xg[c]  = (const char*)Xb  + (size_t)(tile * 128 + prow) * 1024 + qg * 16;
    w1g[c] = (const char*)W1T + (size_t)e * 524288 + (size_t)prow * 1024 + qg * 16;
    w2g[c] = (const char*)W2T + (size_t)e * 131072 + (size_t)prow * 1024 + qg * 16;
  }

  // consumer lane constants (shorts); slot undoes the swizzle
  const int lm = l & 15;
  const int slot = (l >> 4) ^ ((lm >> 1) & 3);
  const int aoff = (wm * 64 + lm) * 32 + slot * 8;
  const int boff = (wn * 64 + lm) * 32 + slot * 8;
  const int hro  = (wm * 64 + lm) * 136 + (l >> 4) * 8;
  const int hwo  = (wm * 64 + (l >> 4) * 4) * 136 + wn * 64 + lm;

  f32x4 acc2[4][4];
#pragma unroll
  for (int i = 0; i < 4; ++i)
#pragma unroll
    for (int j = 0; j < 4; ++j) acc2[i][j] = (f32x4){0.f, 0.f, 0.f, 0.f};

  // prologue: stage hc=0, kk=0 into buf0
#pragma unroll
  for (int c = 0; c < 2; ++c) {
    async_cp16(xg[c],  Xs0 + ldso[c]);
    async_cp16(w1g[c], Ws0 + ldso[c]);
  }

  for (int hc = 0; hc < 4; ++hc) {
    f32x4 acc1[4][4];
#pragma unroll
    for (int i = 0; i < 4; ++i)
#pragma unroll
      for (int j = 0; j < 4; ++j) acc1[i][j] = (f32x4){0.f, 0.f, 0.f, 0.f};

    const size_t w1hc = (size_t)hc * 131072;   // 128 h-rows * 1024B

    // ---- phase 1: hidden[:, hc*128:+128] = X * W1, K=512 in 16 slices ----
#pragma unroll
    for (int kk = 0; kk < 16; ++kk) {
      __syncthreads();                         // drains vmcnt: current bufs ready
      if (kk < 15) {
        short* xb = ((kk + 1) & 1) ? Xs1 : Xs0;
        short* wb = ((kk + 1) & 1) ? Ws1 : Ws0;
#pragma unroll
        for (int c = 0; c < 2; ++c) {
          async_cp16(xg[c] + (kk + 1) * 64,         xb + ldso[c]);
          async_cp16(w1g[c] + w1hc + (kk + 1) * 64, wb + ldso[c]);
        }
      } else {                                 // prefetch phase-2 s=0 into Ws0
#pragma unroll
        for (int c = 0; c < 2; ++c)
          async_cp16(w2g[c] + hc * 256, Ws0 + ldso[c]);
      }
      const short* xb = (kk & 1) ? Xs1 : Xs0;
      const short* wb = (kk & 1) ? Ws1 : Ws0;
      bf16x8 af[4], bfr[4];
#pragma unroll
      for (int t = 0; t < 4; ++t) af[t]  = *(const bf16x8*)(xb + aoff + t * 512);
#pragma unroll
      for (int t = 0; t < 4; ++t) bfr[t] = *(const bf16x8*)(wb + boff + t * 512);
#pragma unroll
      for (int i = 0; i < 4; ++i)
#pragma unroll
        for (int j = 0; j < 4; ++j)
          acc1[i][j] = __builtin_amdgcn_mfma_f32_16x16x32_bf16(af[i], bfr[j], acc1[i][j], 0, 0, 0);
    }

    __syncthreads();   // ALIAS GUARD: kk=15 reads of Xs1 done before HL writes

    // ---- GELU + spill hidden chunk to HL (aliases Xs bufs) ----
    // cvt_pk pairs: 2 conversions / VALU op instead of 4 ops each.
#pragma unroll
    for (int i = 0; i < 4; ++i)
#pragma unroll
      for (int j = 0; j < 4; ++j) {
        float g0 = gelu_f(acc1[i][j][0]), g1 = gelu_f(acc1[i][j][1]);
        float g2 = gelu_f(acc1[i][j][2]), g3 = gelu_f(acc1[i][j][3]);
        uint32_t u01 = pk2(g0, g1), u23 = pk2(g2, g3);
        short* hp = HL + hwo + i * 2176 + j * 16;
        hp[0 * 136] = (short)u01;
        hp[1 * 136] = (short)(u01 >> 16);
        hp[2 * 136] = (short)u23;
        hp[3 * 136] = (short)(u23 >> 16);
      }

    // ---- phase 2: acc2 += gelu(chunk) * W2 slice, K=128 in 4 slices ----
#pragma unroll
    for (int s = 0; s < 4; ++s) {
      __syncthreads();                         // HL writes + W2 slice staged
      if (s < 3) {
        short* wb = ((s + 1) & 1) ? Ws1 : Ws0;
#pragma unroll
        for (int c = 0; c < 2; ++c)
          async_cp16(w2g[c] + hc * 256 + (s + 1) * 64, wb + ldso[c]);
      }
      const short* wb = (s & 1) ? Ws1 : Ws0;
      bf16x8 af[4], bfr[4];
#pragma unroll
      for (int t = 0; t < 4; ++t) af[t]  = *(const bf16x8*)(HL + hro + t * 2176 + s * 32);
#pragma unroll
      for (int t = 0; t < 4; ++t) bfr[t] = *(const bf16x8*)(wb + boff + t * 512);
#pragma unroll
      for (int i = 0; i < 4; ++i)
#pragma unroll
        for (int j = 0; j < 4; ++j)
          acc2[i][j] = __builtin_amdgcn_mfma_f32_16x16x32_bf16(af[i], bfr[j], acc2[i][j], 0, 0, 0);
    }

    if (hc < 3) {
      __syncthreads();   // ALIAS GUARD: HL reads done before staging into Xs0
#pragma unroll
      for (int c = 0; c < 2; ++c) {
        async_cp16(xg[c],                              Xs0 + ldso[c]);
        async_cp16(w1g[c] + (size_t)(hc + 1) * 131072, Ws0 + ldso[c]);
      }
    }
  }

  // ---- epilogue (cvt_pk pairs) ----
  const int d4 = wn * 64 + lm;
  const int lqr = (l >> 4) * 4;
  if (staged) {  // coalesced bf16: OUTs[e][row][d4]
    unsigned short* Ob = (unsigned short*)O;
    const size_t base = ((size_t)e * 8192 + tile * 128 + wm * 64 + lqr) * 128 + d4;
#pragma unroll
    for (int i = 0; i < 4; ++i)
#pragma unroll
      for (int j = 0; j < 4; ++j) {
        uint32_t u01 = pk2(acc2[i][j][0], acc2[i][j][1]);
        uint32_t u23 = pk2(acc2[i][j][2], acc2[i][j][3]);
        unsigned short* op = Ob + base + (size_t)(i * 16) * 128 + j * 16;
        op[0 * 128] = (unsigned short)u01;
        op[1 * 128] = (unsigned short)(u01 >> 16);
        op[2 * 128] = (unsigned short)u23;
        op[3 * 128] = (unsigned short)(u23 >> 16);
      }
  } else {       // direct strided fp32 fallback
    float* Of = (float*)O;
    const size_t rowb = (size_t)tile * 128 + wm * 64 + lqr;
    const size_t base = (rowb * 128 + d4) * 16 + e;
#pragma unroll
    for (int i = 0; i < 4; ++i)
#pragma unroll
      for (int r = 0; r < 4; ++r)
#pragma unroll
        for (int j = 0; j < 4; ++j)
          Of[base + (size_t)(i * 16 + r) * 2048 + j * 256] = acc2[i][j][r];
  }
}

// ---------------------------------------------------------------------------
// Permute: OUT[row][d4*16+e] (fp32) = OUTs[e][row][d4] (bf16). Block = 8 rows.
// R12: final OUT stores are non-temporal (never re-read) -> no L2
// write-allocate fetch for the 67 MB output.
// ---------------------------------------------------------------------------
__global__ __launch_bounds__(256, 2)
void permute_kernel(const unsigned short* __restrict__ OUTs, float* __restrict__ OUT)
{
  __shared__ float T[8 * 16 * 132];     // 67.6 KB
  const int t = threadIdx.x;
  const int r0 = blockIdx.x * 8;
#pragma unroll
  for (int it = 0; it < 8; ++it) {
    int v = it * 256 + t;                       // bf16x8-id, [0,2048)
    int e = v >> 7, rem = v & 127, r = rem >> 4, q8 = rem & 15;
    bf16x8 d = *(const bf16x8*)(OUTs + ((size_t)e * 8192 + r0 + r) * 128 + q8 * 8);
#pragma unroll
    for (int u = 0; u < 8; ++u)
      T[(r * 16 + e) * 132 + q8 * 8 + u] =
          __uint_as_float(((uint32_t)(unsigned short)d[u]) << 16);
  }
  __syncthreads();
#pragma unroll
  for (int it = 0; it < 16; ++it) {
    int u = it * 256 + t;                       // vec4 id, [0,4096)
    int r = u >> 9;                             // [0,8)
    int c4 = (u & 511) * 4;                     // [0,2048)
    int d4 = c4 >> 4, e0 = c4 & 15;
    f32x4 o;
#pragma unroll
    for (int i = 0; i < 4; ++i) o[i] = T[(r * 16 + e0 + i) * 132 + d4];
    __builtin_nontemporal_store(o, (f32x4*)(OUT + (size_t)(r0 + r) * 2048 + c4));
  }
}

extern "C" void kernel_launch(void* const* d_in, const int* in_sizes, int n_in,
                              void* d_out, int out_size, void* d_ws, size_t ws_size,
                              hipStream_t stream)
{
  const float* x  = (const float*)d_in[0];   // fp32 [8192][512]
  const float* w1 = (const float*)d_in[1];   // fp32 [16][512][512]
  const float* w2 = (const float*)d_in[2];   // fp32 [16][512][128]
  float* out = (float*)d_out;                // fp32 [8192][128][16]

  short* Xb  = (short*)d_ws;                 // 8.39 MB
  short* w1t = Xb + 4194304;                 // 8.39 MB
  short* w2t = w1t + 4194304;                // 2.10 MB
  unsigned short* OUTs = (unsigned short*)((char*)d_ws + 18874368);  // bf16, 33.5 MB
  const bool staged = ws_size >= 52428800ULL;

  prep_all<<<dim3(3328), 256, 0, stream>>>(x, w1, w2, Xb, w1t, w2t);
  moe_kernel<<<dim3(1024), 256, 0, stream>>>(Xb, w1t, w2t,
                                             staged ? (void*)OUTs : (void*)out,
                                             staged ? 1 : 0);
  if (staged)
    permute_kernel<<<dim3(1024), 256, 0, stream>>>(OUTs, out);
}

// Round 7
// 235.096 us; speedup vs baseline: 1.4524x; 1.0053x over previous
//
#include <hip/hip_runtime.h>
#include <stdint.h>

typedef short bf16x8 __attribute__((ext_vector_type(8)));
typedef float f32x4 __attribute__((ext_vector_type(4)));

__device__ __forceinline__ void async_cp16(const void* g, short* lds) {
  __builtin_amdgcn_global_load_lds(
      (const __attribute__((address_space(1))) void*)g,
      (__attribute__((address_space(3))) void*)lds, 16, 0, 0);
}

// tanh-approx GELU via sigmoid; |err| < ~1e-3 abs, threshold is 4.3e-2.
__device__ __forceinline__ float gelu_f(float v) {
  float z = 1.5957691216057308f * (v + 0.044715f * v * v * v);
  return __fdividef(v, 1.0f + __expf(-z));
}

__device__ __forceinline__ short f2bf(float x) {  // RNE f32->bf16
  uint32_t u = __float_as_uint(x);
  u += 0x7fffu + ((u >> 16) & 1u);
  return (short)(u >> 16);
}

// ---------------------------------------------------------------------------
// One-launch prep: fp32 -> bf16 cast of X + per-expert transposes of W1/W2.
// (R7-exact: R12's cvt_pk/NT variants were neutral-negative, reverted.)
// ---------------------------------------------------------------------------
__global__ __launch_bounds__(256)
void prep_all(const float* __restrict__ x, const float* __restrict__ w1,
              const float* __restrict__ w2, short* __restrict__ Xb,
              short* __restrict__ w1t, short* __restrict__ w2t)
{
  __shared__ __align__(16) short T[64][72];
  const int b = blockIdx.x;
  const int t = threadIdx.x;

  if (b < 2048) {                       // ---- X cast ----
    const int idx = (b * 256 + t) * 8;
    bf16x8 o;
#pragma unroll
    for (int u = 0; u < 8; ++u) o[u] = f2bf(x[idx + u]);
    *(bf16x8*)(Xb + idx) = o;
    return;
  }

  const float* src; short* dst; int e, r0, c0, R, C;
  if (b < 3072) {                       // ---- W1 ----
    int idx = b - 2048; e = idx >> 6; int rem = idx & 63;
    r0 = (rem >> 3) * 64; c0 = (rem & 7) * 64; R = 512; C = 512;
    src = w1; dst = w1t;
  } else {                              // ---- W2 ----
    int idx = b - 3072; e = idx >> 4; int rem = idx & 15;
    r0 = (rem >> 1) * 64; c0 = (rem & 1) * 64; R = 512; C = 128;
    src = w2; dst = w2t;
  }
  const float* s = src + (size_t)e * R * C;
  short* d       = dst + (size_t)e * R * C;
  const int i = t >> 3, j8 = t & 7;
#pragma unroll
  for (int p = 0; p < 2; ++p) {
    int ii = i + p * 32;
#pragma unroll
    for (int u = 0; u < 8; ++u)
      T[ii][j8 * 8 + u] = f2bf(s[(size_t)(r0 + ii) * C + c0 + j8 * 8 + u]);
  }
  __syncthreads();
#pragma unroll
  for (int p = 0; p < 2; ++p) {
    int ii = i + p * 32;
    bf16x8 v;
#pragma unroll
    for (int u = 0; u < 8; ++u) v[u] = T[j8 * 8 + u][ii];
    *(bf16x8*)(d + (size_t)(c0 + ii) * R + r0 + j8 * 8) = v;
  }
}

// ---------------------------------------------------------------------------
// Fused experts. Block = 128-token tile x 1 expert, 4 waves (2x2 of 64x64).
// R13 (resubmitted after infra failure): phase-1 is R7-BYTE-IDENTICAL
// (staging pattern, BK=32 dbuf, 16 __syncthreads — every mutation of it
// regressed in R8-R12). Structural changes OUTSIDE phase-1 only:
//  - HL disjoint at SM+16384 (LDS 67.6 KB; R10 measured same occupancy as
//    51.2 KB -> free). Removes BOTH alias-guard barriers.
//  - W2 via 16 global dwordx4 -> registers (byte-identical elements to the
//    LDS path, algebra-verified). Phase-2 has ZERO barriers: B1 (HL
//    publish) then 64 MFMAs straight. s0/s1 loads before GELU (covered),
//    s2/s3 after B1 (covered by s0/s1 compute, per-wave counted waits).
//  - next-hc X/W1 restage issued right after B1: covered by all of
//    phase-2 (R7 issued it with ZERO cover at every hc boundary).
//  - T5 setprio(1/0) around each 16-MFMA cluster (2 independent
//    blocks/CU = role diversity; attn-like regime).
// Barriers/hc: 22 -> 17. No DMA outstanding at endpgm (restage guarded
// hc<3; W2-reg loads drained at B1).
// ---------------------------------------------------------------------------
__global__ __launch_bounds__(256, 2)
void moe_kernel(const short* __restrict__ Xb, const short* __restrict__ W1T,
                const short* __restrict__ W2T, void* __restrict__ O, int staged)
{
  __shared__ __align__(16) short SM[33792];        // 67.6 KB
  short* const Ws0 = SM;                           // [128][32]
  short* const Ws1 = SM + 4096;
  short* const Xs0 = SM + 8192;
  short* const Xs1 = SM + 12288;
  short* const HL  = SM + 16384;                   // [128][136], DISJOINT

  const int tid = threadIdx.x;
  const int l = tid & 63, w = tid >> 6;
  const int wm = w & 1, wn = w >> 1;
  const int e    = blockIdx.x >> 6;     // e-outer (L2 locality per XCD)
  const int tile = blockIdx.x & 63;

  // staging lane constants (lane -> base + lane*16B, packed [row][32 shorts])
  const int lrow = l >> 2, lq = l & 3;
  int ldso[2];
  const char *xg[2], *w1g[2];
#pragma unroll
  for (int c = 0; c < 2; ++c) {
    int prow = w * 32 + c * 16 + lrow;                      // 0..127
    int qg = lq ^ ((prow >> 1) & 3);                        // XOR quad swizzle
    ldso[c] = (w * 32 + c * 16) * 32;
    xg[c]  = (const char*)Xb  + (size_t)(tile * 128 + prow) * 1024 + qg * 16;
    w1g[c] = (const char*)W1T + (size_t)e * 524288 + (size_t)prow * 1024 + qg * 16;
  }

  // consumer lane constants (shorts); slot undoes the swizzle
  const int lm = l & 15;
  const int slot = (l >> 4) ^ ((lm >> 1) & 3);
  const int aoff = (wm * 64 + lm) * 32 + slot * 8;
  const int boff = (wn * 64 + lm) * 32 + slot * 8;
  const int hro  = (wm * 64 + lm) * 136 + (l >> 4) * 8;
  const int hwo  = (wm * 64 + (l >> 4) * 4) * 136 + wn * 64 + lm;

  // W2 direct-to-register base: row (wn*64+lm), h-bytes g*16 within slice.
  // Equivalent elements to the old LDS path: W2T[e][row+t*16][hc*256+s*64+g*16].
  const char* w2r_base = (const char*)W2T + (size_t)e * 131072 +
                         (size_t)(wn * 64 + lm) * 1024 + (l >> 4) * 16;

  f32x4 acc2[4][4];
#pragma unroll
  for (int i = 0; i < 4; ++i)
#pragma unroll
    for (int j = 0; j < 4; ++j) acc2[i][j] = (f32x4){0.f, 0.f, 0.f, 0.f};

  // prologue: stage hc=0, kk=0 into buf0
#pragma unroll
  for (int c = 0; c < 2; ++c) {
    async_cp16(xg[c],  Xs0 + ldso[c]);
    async_cp16(w1g[c], Ws0 + ldso[c]);
  }

  for (int hc = 0; hc < 4; ++hc) {
    f32x4 acc1[4][4];
#pragma unroll
    for (int i = 0; i < 4; ++i)
#pragma unroll
      for (int j = 0; j < 4; ++j) acc1[i][j] = (f32x4){0.f, 0.f, 0.f, 0.f};

    const size_t w1hc = (size_t)hc * 131072;   // 128 h-rows * 1024B

    // ---- phase 1: hidden[:, hc*128:+128] = X * W1, K=512 in 16 slices ----
    // (R7-identical except kk=15 no longer stages W2.)
#pragma unroll
    for (int kk = 0; kk < 16; ++kk) {
      __syncthreads();                         // drains vmcnt: current bufs ready
      if (kk < 15) {
        short* xb = ((kk + 1) & 1) ? Xs1 : Xs0;
        short* wb = ((kk + 1) & 1) ? Ws1 : Ws0;
#pragma unroll
        for (int c = 0; c < 2; ++c) {
          async_cp16(xg[c] + (kk + 1) * 64,         xb + ldso[c]);
          async_cp16(w1g[c] + w1hc + (kk + 1) * 64, wb + ldso[c]);
        }
      }
      const short* xb = (kk & 1) ? Xs1 : Xs0;
      const short* wb = (kk & 1) ? Ws1 : Ws0;
      bf16x8 af[4], bfr[4];
#pragma unroll
      for (int t = 0; t < 4; ++t) af[t]  = *(const bf16x8*)(xb + aoff + t * 512);
#pragma unroll
      for (int t = 0; t < 4; ++t) bfr[t] = *(const bf16x8*)(wb + boff + t * 512);
      __builtin_amdgcn_s_setprio(1);
#pragma unroll
      for (int i = 0; i < 4; ++i)
#pragma unroll
        for (int j = 0; j < 4; ++j)
          acc1[i][j] = __builtin_amdgcn_mfma_f32_16x16x32_bf16(af[i], bfr[j], acc1[i][j], 0, 0, 0);
      __builtin_amdgcn_s_setprio(0);
    }

    // ---- W2 s=0,1 -> registers (latency covered by GELU; drained at B1) ----
    bf16x8 w2r[4][4];
#pragma unroll
    for (int s = 0; s < 2; ++s)
#pragma unroll
      for (int t = 0; t < 4; ++t)
        w2r[s][t] = *(const bf16x8*)(w2r_base + (size_t)t * 16384 + hc * 256 + s * 64);

    // ---- GELU -> HL (disjoint: no alias guard; kk=15 readers touch only
    // Xs1/Ws1; own-wave acc1 is a register dep) ----
#pragma unroll
    for (int i = 0; i < 4; ++i)
#pragma unroll
      for (int j = 0; j < 4; ++j)
#pragma unroll
        for (int r = 0; r < 4; ++r)
          HL[hwo + i * 2176 + r * 136 + j * 16] = f2bf(gelu_f(acc1[i][j][r]));

    __syncthreads();   // B1: HL published cross-wave; w2r s0/s1 drained

    if (hc < 3) {      // next-hc kk=0 restage: covered by ALL of phase-2,
                       // drains at next kk=0 barrier (R7 had zero cover here)
#pragma unroll
      for (int c = 0; c < 2; ++c) {
        async_cp16(xg[c],                              Xs0 + ldso[c]);
        async_cp16(w1g[c] + (size_t)(hc + 1) * 131072, Ws0 + ldso[c]);
      }
    }

    // ---- W2 s=2,3 -> registers (covered by s0/s1 compute via per-wave
    // counted waits; no barrier involved) ----
#pragma unroll
    for (int s = 2; s < 4; ++s)
#pragma unroll
      for (int t = 0; t < 4; ++t)
        w2r[s][t] = *(const bf16x8*)(w2r_base + (size_t)t * 16384 + hc * 256 + s * 64);

    // ---- phase 2: acc2 += gelu(chunk) * W2, K=128, ZERO barriers ----
#pragma unroll
    for (int s = 0; s < 4; ++s) {
      bf16x8 af[4];
#pragma unroll
      for (int t = 0; t < 4; ++t) af[t] = *(const bf16x8*)(HL + hro + t * 2176 + s * 32);
      __builtin_amdgcn_s_setprio(1);
#pragma unroll
      for (int i = 0; i < 4; ++i)
#pragma unroll
        for (int j = 0; j < 4; ++j)
          acc2[i][j] = __builtin_amdgcn_mfma_f32_16x16x32_bf16(af[i], w2r[s][j], acc2[i][j], 0, 0, 0);
      __builtin_amdgcn_s_setprio(0);
    }
  }

  // ---- epilogue (R7-exact; no DMA outstanding: hc=3 issued no restage,
  // its last DMAs drained at hc=3's kk=0 barrier) ----
  const int d4 = wn * 64 + lm;
  const int lqr = (l >> 4) * 4;
  if (staged) {  // coalesced bf16: OUTs[e][row][d4]
    unsigned short* Ob = (unsigned short*)O;
    const size_t base = ((size_t)e * 8192 + tile * 128 + wm * 64 + lqr) * 128 + d4;
#pragma unroll
    for (int i = 0; i < 4; ++i)
#pragma unroll
      for (int r = 0; r < 4; ++r)
#pragma unroll
        for (int j = 0; j < 4; ++j)
          Ob[base + (size_t)(i * 16 + r) * 128 + j * 16] = (unsigned short)f2bf(acc2[i][j][r]);
  } else {       // direct strided fp32 fallback
    float* Of = (float*)O;
    const size_t rowb = (size_t)tile * 128 + wm * 64 + lqr;
    const size_t base = (rowb * 128 + d4) * 16 + e;
#pragma unroll
    for (int i = 0; i < 4; ++i)
#pragma unroll
      for (int r = 0; r < 4; ++r)
#pragma unroll
        for (int j = 0; j < 4; ++j)
          Of[base + (size_t)(i * 16 + r) * 2048 + j * 256] = acc2[i][j][r];
  }
}

// ---------------------------------------------------------------------------
// Permute: OUT[row][d4*16+e] (fp32) = OUTs[e][row][d4] (bf16). Block = 8 rows.
// (R7-exact: NT-store variant reverted.)
// ---------------------------------------------------------------------------
__global__ __launch_bounds__(256, 2)
void permute_kernel(const unsigned short* __restrict__ OUTs, float* __restrict__ OUT)
{
  __shared__ float T[8 * 16 * 132];     // 67.6 KB
  const int t = threadIdx.x;
  const int r0 = blockIdx.x * 8;
#pragma unroll
  for (int it = 0; it < 8; ++it) {
    int v = it * 256 + t;                       // bf16x8-id, [0,2048)
    int e = v >> 7, rem = v & 127, r = rem >> 4, q8 = rem & 15;
    bf16x8 d = *(const bf16x8*)(OUTs + ((size_t)e * 8192 + r0 + r) * 128 + q8 * 8);
#pragma unroll
    for (int u = 0; u < 8; ++u)
      T[(r * 16 + e) * 132 + q8 * 8 + u] =
          __uint_as_float(((uint32_t)(unsigned short)d[u]) << 16);
  }
  __syncthreads();
#pragma unroll
  for (int it = 0; it < 16; ++it) {
    int u = it * 256 + t;                       // vec4 id, [0,4096)
    int r = u >> 9;                             // [0,8)
    int c4 = (u & 511) * 4;                     // [0,2048)
    int d4 = c4 >> 4, e0 = c4 & 15;
    f32x4 o;
#pragma unroll
    for (int i = 0; i < 4; ++i) o[i] = T[(r * 16 + e0 + i) * 132 + d4];
    *(f32x4*)(OUT + (size_t)(r0 + r) * 2048 + c4) = o;
  }
}

extern "C" void kernel_launch(void* const* d_in, const int* in_sizes, int n_in,
                              void* d_out, int out_size, void* d_ws, size_t ws_size,
                              hipStream_t stream)
{
  const float* x  = (const float*)d_in[0];   // fp32 [8192][512]
  const float* w1 = (const float*)d_in[1];   // fp32 [16][512][512]
  const float* w2 = (const float*)d_in[2];   // fp32 [16][512][128]
  float* out = (float*)d_out;                // fp32 [8192][128][16]

  short* Xb  = (short*)d_ws;                 // 8.39 MB
  short* w1t = Xb + 4194304;                 // 8.39 MB
  short* w2t = w1t + 4194304;                // 2.10 MB
  unsigned short* OUTs = (unsigned short*)((char*)d_ws + 18874368);  // bf16, 33.5 MB
  const bool staged = ws_size >= 52428800ULL;

  prep_all<<<dim3(3328), 256, 0, stream>>>(x, w1, w2, Xb, w1t, w2t);
  moe_kernel<<<dim3(1024), 256, 0, stream>>>(Xb, w1t, w2t,
                                             staged ? (void*)OUTs : (void*)out,
                                             staged ? 1 : 0);
  if (staged)
    permute_kernel<<<dim3(1024), 256, 0, stream>>>(OUTs, out);
}

// Round 8
// 217.961 us; speedup vs baseline: 1.5666x; 1.0786x over previous
//
#include <hip/hip_runtime.h>
#include <stdint.h>

typedef short bf16x8 __attribute__((ext_vector_type(8)));
typedef float f32x4 __attribute__((ext_vector_type(4)));

__device__ __forceinline__ void async_cp16(const void* g, short* lds) {
  __builtin_amdgcn_global_load_lds(
      (const __attribute__((address_space(1))) void*)g,
      (__attribute__((address_space(3))) void*)lds, 16, 0, 0);
}

// tanh-approx GELU via sigmoid; |err| < ~1e-3 abs, threshold is 4.3e-2.
__device__ __forceinline__ float gelu_f(float v) {
  float z = 1.5957691216057308f * (v + 0.044715f * v * v * v);
  return __fdividef(v, 1.0f + __expf(-z));
}

__device__ __forceinline__ short f2bf(float x) {  // RNE f32->bf16
  uint32_t u = __float_as_uint(x);
  u += 0x7fffu + ((u >> 16) & 1u);
  return (short)(u >> 16);
}

// ---------------------------------------------------------------------------
// One-launch prep: fp32 -> bf16 cast of X + per-expert transposes of W1/W2.
// (R7-exact.)
// ---------------------------------------------------------------------------
__global__ __launch_bounds__(256)
void prep_all(const float* __restrict__ x, const float* __restrict__ w1,
              const float* __restrict__ w2, short* __restrict__ Xb,
              short* __restrict__ w1t, short* __restrict__ w2t)
{
  __shared__ __align__(16) short T[64][72];
  const int b = blockIdx.x;
  const int t = threadIdx.x;

  if (b < 2048) {                       // ---- X cast ----
    const int idx = (b * 256 + t) * 8;
    bf16x8 o;
#pragma unroll
    for (int u = 0; u < 8; ++u) o[u] = f2bf(x[idx + u]);
    *(bf16x8*)(Xb + idx) = o;
    return;
  }

  const float* src; short* dst; int e, r0, c0, R, C;
  if (b < 3072) {                       // ---- W1 ----
    int idx = b - 2048; e = idx >> 6; int rem = idx & 63;
    r0 = (rem >> 3) * 64; c0 = (rem & 7) * 64; R = 512; C = 512;
    src = w1; dst = w1t;
  } else {                              // ---- W2 ----
    int idx = b - 3072; e = idx >> 4; int rem = idx & 15;
    r0 = (rem >> 1) * 64; c0 = (rem & 1) * 64; R = 512; C = 128;
    src = w2; dst = w2t;
  }
  const float* s = src + (size_t)e * R * C;
  short* d       = dst + (size_t)e * R * C;
  const int i = t >> 3, j8 = t & 7;
#pragma unroll
  for (int p = 0; p < 2; ++p) {
    int ii = i + p * 32;
#pragma unroll
    for (int u = 0; u < 8; ++u)
      T[ii][j8 * 8 + u] = f2bf(s[(size_t)(r0 + ii) * C + c0 + j8 * 8 + u]);
  }
  __syncthreads();
#pragma unroll
  for (int p = 0; p < 2; ++p) {
    int ii = i + p * 32;
    bf16x8 v;
#pragma unroll
    for (int u = 0; u < 8; ++u) v[u] = T[j8 * 8 + u][ii];
    *(bf16x8*)(d + (size_t)(c0 + ii) * R + r0 + j8 * 8) = v;
  }
}

// ---------------------------------------------------------------------------
// Fused experts. Block = 128-token tile x 1 expert, 4 waves (2x2 of 64x64).
// R14 = R7 byte-exact EXCEPT: HL moved to disjoint LDS (SM+16384, total
// 67.6 KB — R10/R13 both measured identical occupancy vs 51.2 KB), which
// makes the pre-GELU ALIAS GUARD removable (HL no longer overlaps Xs0/Xs1;
// kk=15's Xs1/Ws1 reads aren't overwritten until next-hc kk=1; GELU now
// also covers the kk=15-issued W2-s0 DMA that R7 drained cold).
// The post-phase-2 guard STAYS: restage into Xs0/Ws0 must wait for all
// waves' s=2 Ws0 reads (cross-wave hazard).
// Session ledger (why nothing else is touched): R8/R10 counted-vmcnt −16%
// (loads are L2-hot; drain was never the stall; junk tail +45MB FETCH);
// R11 BK=64+restage −88% (FETCH 56->268MB); R12 cvt_pk VALU diet −3%
// (VALU issue not critical path); R13 reg-W2 −14% (single vmcnt counter
// serializes restage into phase-2; 8x W2 traffic). W2 stays in LDS;
// phase-1 staging/barriers are the measured optimum.
// staged==1: O = ws bf16 [16 e][8192 row][128 d4] (coalesced).
// staged==0: O = out fp32 [row][d4][16 e] (strided fallback).
// ---------------------------------------------------------------------------
__global__ __launch_bounds__(256, 2)
void moe_kernel(const short* __restrict__ Xb, const short* __restrict__ W1T,
                const short* __restrict__ W2T, void* __restrict__ O, int staged)
{
  __shared__ __align__(16) short SM[33792];        // 67.6 KB
  short* const Ws0 = SM;                           // [128][32]
  short* const Ws1 = SM + 4096;
  short* const Xs0 = SM + 8192;
  short* const Xs1 = SM + 12288;
  short* const HL  = SM + 16384;                   // [128][136], DISJOINT

  const int tid = threadIdx.x;
  const int l = tid & 63, w = tid >> 6;
  const int wm = w & 1, wn = w >> 1;
  const int e    = blockIdx.x >> 6;     // e-outer (L2 locality per XCD)
  const int tile = blockIdx.x & 63;

  // staging lane constants (lane -> base + lane*16B, packed [row][32 shorts])
  const int lrow = l >> 2, lq = l & 3;
  int ldso[2];
  const char *xg[2], *w1g[2], *w2g[2];
#pragma unroll
  for (int c = 0; c < 2; ++c) {
    int prow = w * 32 + c * 16 + lrow;                      // 0..127
    int qg = lq ^ ((prow >> 1) & 3);                        // XOR quad swizzle
    ldso[c] = (w * 32 + c * 16) * 32;
    xg[c]  = (const char*)Xb  + (size_t)(tile * 128 + prow) * 1024 + qg * 16;
    w1g[c] = (const char*)W1T + (size_t)e * 524288 + (size_t)prow * 1024 + qg * 16;
    w2g[c] = (const char*)W2T + (size_t)e * 131072 + (size_t)prow * 1024 + qg * 16;
  }

  // consumer lane constants (shorts); slot undoes the swizzle
  const int lm = l & 15;
  const int slot = (l >> 4) ^ ((lm >> 1) & 3);
  const int aoff = (wm * 64 + lm) * 32 + slot * 8;
  const int boff = (wn * 64 + lm) * 32 + slot * 8;
  const int hro  = (wm * 64 + lm) * 136 + (l >> 4) * 8;
  const int hwo  = (wm * 64 + (l >> 4) * 4) * 136 + wn * 64 + lm;

  f32x4 acc2[4][4];
#pragma unroll
  for (int i = 0; i < 4; ++i)
#pragma unroll
    for (int j = 0; j < 4; ++j) acc2[i][j] = (f32x4){0.f, 0.f, 0.f, 0.f};

  // prologue: stage hc=0, kk=0 into buf0
#pragma unroll
  for (int c = 0; c < 2; ++c) {
    async_cp16(xg[c],  Xs0 + ldso[c]);
    async_cp16(w1g[c], Ws0 + ldso[c]);
  }

  for (int hc = 0; hc < 4; ++hc) {
    f32x4 acc1[4][4];
#pragma unroll
    for (int i = 0; i < 4; ++i)
#pragma unroll
      for (int j = 0; j < 4; ++j) acc1[i][j] = (f32x4){0.f, 0.f, 0.f, 0.f};

    const size_t w1hc = (size_t)hc * 131072;   // 128 h-rows * 1024B

    // ---- phase 1: hidden[:, hc*128:+128] = X * W1, K=512 in 16 slices ----
#pragma unroll
    for (int kk = 0; kk < 16; ++kk) {
      __syncthreads();                         // drains vmcnt: current bufs ready
      if (kk < 15) {
        short* xb = ((kk + 1) & 1) ? Xs1 : Xs0;
        short* wb = ((kk + 1) & 1) ? Ws1 : Ws0;
#pragma unroll
        for (int c = 0; c < 2; ++c) {
          async_cp16(xg[c] + (kk + 1) * 64,         xb + ldso[c]);
          async_cp16(w1g[c] + w1hc + (kk + 1) * 64, wb + ldso[c]);
        }
      } else {                                 // prefetch phase-2 s=0 into Ws0
#pragma unroll
        for (int c = 0; c < 2; ++c)
          async_cp16(w2g[c] + hc * 256, Ws0 + ldso[c]);
      }
      const short* xb = (kk & 1) ? Xs1 : Xs0;
      const short* wb = (kk & 1) ? Ws1 : Ws0;
      bf16x8 af[4], bfr[4];
#pragma unroll
      for (int t = 0; t < 4; ++t) af[t]  = *(const bf16x8*)(xb + aoff + t * 512);
#pragma unroll
      for (int t = 0; t < 4; ++t) bfr[t] = *(const bf16x8*)(wb + boff + t * 512);
#pragma unroll
      for (int i = 0; i < 4; ++i)
#pragma unroll
        for (int j = 0; j < 4; ++j)
          acc1[i][j] = __builtin_amdgcn_mfma_f32_16x16x32_bf16(af[i], bfr[j], acc1[i][j], 0, 0, 0);
    }

    // ---- GELU + spill hidden chunk to HL (DISJOINT: no alias guard.
    // GELU covers the in-flight W2-s0 DMA that R7 drained cold here.
    // kk=15's Xs1/Ws1 reads are register-consumed before any overwrite
    // (next write to Xs1/Ws1 is next-hc kk=1, many barriers away). ----
#pragma unroll
    for (int i = 0; i < 4; ++i)
#pragma unroll
      for (int j = 0; j < 4; ++j)
#pragma unroll
        for (int r = 0; r < 4; ++r)
          HL[hwo + i * 2176 + r * 136 + j * 16] = f2bf(gelu_f(acc1[i][j][r]));

    // ---- phase 2: acc2 += gelu(chunk) * W2 slice, K=128 in 4 slices ----
#pragma unroll
    for (int s = 0; s < 4; ++s) {
      __syncthreads();                         // HL writes + W2 slice staged
      if (s < 3) {
        short* wb = ((s + 1) & 1) ? Ws1 : Ws0;
#pragma unroll
        for (int c = 0; c < 2; ++c)
          async_cp16(w2g[c] + hc * 256 + (s + 1) * 64, wb + ldso[c]);
      }
      const short* wb = (s & 1) ? Ws1 : Ws0;
      bf16x8 af[4], bfr[4];
#pragma unroll
      for (int t = 0; t < 4; ++t) af[t]  = *(const bf16x8*)(HL + hro + t * 2176 + s * 32);
#pragma unroll
      for (int t = 0; t < 4; ++t) bfr[t] = *(const bf16x8*)(wb + boff + t * 512);
#pragma unroll
      for (int i = 0; i < 4; ++i)
#pragma unroll
        for (int j = 0; j < 4; ++j)
          acc2[i][j] = __builtin_amdgcn_mfma_f32_16x16x32_bf16(af[i], bfr[j], acc2[i][j], 0, 0, 0);
    }

    if (hc < 3) {
      __syncthreads();   // GUARD: all waves' s=2 Ws0 reads done before restage
#pragma unroll
      for (int c = 0; c < 2; ++c) {
        async_cp16(xg[c],                              Xs0 + ldso[c]);
        async_cp16(w1g[c] + (size_t)(hc + 1) * 131072, Ws0 + ldso[c]);
      }
    }
  }

  // ---- epilogue (R7-exact) ----
  const int d4 = wn * 64 + lm;
  const int lqr = (l >> 4) * 4;
  if (staged) {  // coalesced bf16: OUTs[e][row][d4]
    unsigned short* Ob = (unsigned short*)O;
    const size_t base = ((size_t)e * 8192 + tile * 128 + wm * 64 + lqr) * 128 + d4;
#pragma unroll
    for (int i = 0; i < 4; ++i)
#pragma unroll
      for (int r = 0; r < 4; ++r)
#pragma unroll
        for (int j = 0; j < 4; ++j)
          Ob[base + (size_t)(i * 16 + r) * 128 + j * 16] = (unsigned short)f2bf(acc2[i][j][r]);
  } else {       // direct strided fp32 fallback
    float* Of = (float*)O;
    const size_t rowb = (size_t)tile * 128 + wm * 64 + lqr;
    const size_t base = (rowb * 128 + d4) * 16 + e;
#pragma unroll
    for (int i = 0; i < 4; ++i)
#pragma unroll
      for (int r = 0; r < 4; ++r)
#pragma unroll
        for (int j = 0; j < 4; ++j)
          Of[base + (size_t)(i * 16 + r) * 2048 + j * 256] = acc2[i][j][r];
  }
}

// ---------------------------------------------------------------------------
// Permute: OUT[row][d4*16+e] (fp32) = OUTs[e][row][d4] (bf16). Block = 8 rows.
// (R7-exact.)
// ---------------------------------------------------------------------------
__global__ __launch_bounds__(256, 2)
void permute_kernel(const unsigned short* __restrict__ OUTs, float* __restrict__ OUT)
{
  __shared__ float T[8 * 16 * 132];     // 67.6 KB
  const int t = threadIdx.x;
  const int r0 = blockIdx.x * 8;
#pragma unroll
  for (int it = 0; it < 8; ++it) {
    int v = it * 256 + t;                       // bf16x8-id, [0,2048)
    int e = v >> 7, rem = v & 127, r = rem >> 4, q8 = rem & 15;
    bf16x8 d = *(const bf16x8*)(OUTs + ((size_t)e * 8192 + r0 + r) * 128 + q8 * 8);
#pragma unroll
    for (int u = 0; u < 8; ++u)
      T[(r * 16 + e) * 132 + q8 * 8 + u] =
          __uint_as_float(((uint32_t)(unsigned short)d[u]) << 16);
  }
  __syncthreads();
#pragma unroll
  for (int it = 0; it < 16; ++it) {
    int u = it * 256 + t;                       // vec4 id, [0,4096)
    int r = u >> 9;                             // [0,8)
    int c4 = (u & 511) * 4;                     // [0,2048)
    int d4 = c4 >> 4, e0 = c4 & 15;
    f32x4 o;
#pragma unroll
    for (int i = 0; i < 4; ++i) o[i] = T[(r * 16 + e0 + i) * 132 + d4];
    *(f32x4*)(OUT + (size_t)(r0 + r) * 2048 + c4) = o;
  }
}

extern "C" void kernel_launch(void* const* d_in, const int* in_sizes, int n_in,
                              void* d_out, int out_size, void* d_ws, size_t ws_size,
                              hipStream_t stream)
{
  const float* x  = (const float*)d_in[0];   // fp32 [8192][512]
  const float* w1 = (const float*)d_in[1];   // fp32 [16][512][512]
  const float* w2 = (const float*)d_in[2];   // fp32 [16][512][128]
  float* out = (float*)d_out;                // fp32 [8192][128][16]

  short* Xb  = (short*)d_ws;                 // 8.39 MB
  short* w1t = Xb + 4194304;                 // 8.39 MB
  short* w2t = w1t + 4194304;                // 2.10 MB
  unsigned short* OUTs = (unsigned short*)((char*)d_ws + 18874368);  // bf16, 33.5 MB
  const bool staged = ws_size >= 52428800ULL;

  prep_all<<<dim3(3328), 256, 0, stream>>>(x, w1, w2, Xb, w1t, w2t);
  moe_kernel<<<dim3(1024), 256, 0, stream>>>(Xb, w1t, w2t,
                                             staged ? (void*)OUTs : (void*)out,
                                             staged ? 1 : 0);
  if (staged)
    permute_kernel<<<dim3(1024), 256, 0, stream>>>(OUTs, out);
}